// Round 5
// baseline (1023.472 us; speedup 1.0000x reference)
//
#include <hip/hip_runtime.h>
#include <math.h>

constexpr int V0_ = 2000, V1_ = 1500, V2_ = 500;
constexpr int D_ = 256, T_ = 16, P_ = 512;
constexpr int LD_ = 24, LP_ = 16, LM_ = 24;
constexpr int NPAT = P_ + 1;        // 513 (512 mem + 1 query)
constexpr int NV   = NPAT * T_;     // 8208 visits
constexpr int NM   = P_ * (T_ - 1); // 7680 memory rows
constexpr int NQ   = T_ - 1;        // 15 query rows
constexpr int NROWS = NPAT * NQ;    // 7695 encoder rows (M rows then Q rows)
constexpr float THRESH_ = 0.8f;
constexpr float EPS_ = 1e-6f;

__device__ __forceinline__ float sigmoidf_(float x) { return 1.0f / (1.0f + expf(-x)); }

// ---------------- K1: embedding gather-sums ----------------
__global__ void embed_kernel(const int* __restrict__ qd, const int* __restrict__ qp,
                             const int* __restrict__ qm, const int* __restrict__ md,
                             const int* __restrict__ mp, const int* __restrict__ mm,
                             const float* __restrict__ emb,
                             float* __restrict__ e_nomed, float* __restrict__ e_full) {
  int b = blockIdx.x;           // 0..NV-1
  int p = b / T_, t = b % T_;
  int tid = threadIdx.x;
  __shared__ int codes[64];
  if (tid < 64) {
    int c;
    if (tid < LD_) {
      c = (p < P_) ? md[(p * T_ + t) * LD_ + tid] : qd[t * LD_ + tid];
    } else if (tid < LD_ + LP_) {
      int i = tid - LD_;
      c = ((p < P_) ? mp[(p * T_ + t) * LP_ + i] : qp[t * LP_ + i]) + V0_;
    } else {
      int i = tid - LD_ - LP_;
      c = ((p < P_) ? mm[(p * T_ + t) * LM_ + i] : qm[t * LM_ + i]) + V0_ + V1_;
    }
    codes[tid] = c;
  }
  __syncthreads();
  float s0 = 0.f, s1 = 0.f;
  #pragma unroll 8
  for (int i = 0; i < LD_ + LP_; ++i) s0 += emb[codes[i] * D_ + tid];
  #pragma unroll 8
  for (int i = LD_ + LP_; i < 64; ++i) s1 += emb[codes[i] * D_ + tid];
  e_nomed[(size_t)b * D_ + tid] = s0;
  e_full[(size_t)b * D_ + tid]  = s0 + s1;
}

// ---------------- K2: C[M,N] = A[M,256] * B[N,256]^T + bias[N] ----------------
#define BM 128
#define BN 64
#define BK 32
__global__ void gemm_nt_bias(const float* __restrict__ A, const float* __restrict__ B,
                             const float* __restrict__ bias, float* __restrict__ C,
                             int M, int N) {
  const int K = 256;
  __shared__ float As[BK][BM + 4];
  __shared__ float Bs[BK][BN + 4];
  int tid = threadIdx.x;
  int tx = tid & 15, ty = tid >> 4;
  int r0 = blockIdx.y * BM;
  int c0 = blockIdx.x * BN;
  float acc[8][4];
  #pragma unroll
  for (int i = 0; i < 8; ++i)
    #pragma unroll
    for (int j = 0; j < 4; ++j) acc[i][j] = 0.f;

  for (int k0 = 0; k0 < K; k0 += BK) {
    #pragma unroll
    for (int i = 0; i < 4; ++i) {           // A tile 128x32
      int flat = i * 256 + tid;             // one float4 each
      int r = flat >> 3;
      int kq = flat & 7;
      float4 v = make_float4(0.f, 0.f, 0.f, 0.f);
      if (r0 + r < M) v = *(const float4*)(A + (size_t)(r0 + r) * K + k0 + kq * 4);
      As[kq * 4 + 0][r] = v.x; As[kq * 4 + 1][r] = v.y;
      As[kq * 4 + 2][r] = v.z; As[kq * 4 + 3][r] = v.w;
    }
    #pragma unroll
    for (int i = 0; i < 2; ++i) {           // B tile 64x32 (N%64==0, no guard)
      int flat = i * 256 + tid;
      int r = flat >> 3;
      int kq = flat & 7;
      float4 v = *(const float4*)(B + (size_t)(c0 + r) * K + k0 + kq * 4);
      Bs[kq * 4 + 0][r] = v.x; Bs[kq * 4 + 1][r] = v.y;
      Bs[kq * 4 + 2][r] = v.z; Bs[kq * 4 + 3][r] = v.w;
    }
    __syncthreads();
    #pragma unroll
    for (int kk = 0; kk < BK; ++kk) {
      float4 a0 = *(const float4*)&As[kk][ty * 8];
      float4 a1 = *(const float4*)&As[kk][ty * 8 + 4];
      float4 bv = *(const float4*)&Bs[kk][tx * 4];
      float av[8] = {a0.x, a0.y, a0.z, a0.w, a1.x, a1.y, a1.z, a1.w};
      float bw[4] = {bv.x, bv.y, bv.z, bv.w};
      #pragma unroll
      for (int i = 0; i < 8; ++i)
        #pragma unroll
        for (int j = 0; j < 4; ++j) acc[i][j] = fmaf(av[i], bw[j], acc[i][j]);
    }
    __syncthreads();
  }
  float bv0 = bias[c0 + tx * 4 + 0], bv1 = bias[c0 + tx * 4 + 1];
  float bv2 = bias[c0 + tx * 4 + 2], bv3 = bias[c0 + tx * 4 + 3];
  #pragma unroll
  for (int i = 0; i < 8; ++i) {
    int r = r0 + ty * 8 + i;
    if (r < M) {
      float4 o = make_float4(acc[i][0] + bv0, acc[i][1] + bv1,
                             acc[i][2] + bv2, acc[i][3] + bv3);
      *(float4*)(C + (size_t)r * N + c0 + tx * 4) = o;
    }
  }
}

// ---------------- K3: one GRU step (d-sliced x patient-sliced) ----------------
__global__ void gru_step(const float* __restrict__ h_in, float* __restrict__ h_out,
                         const float* __restrict__ gx, const float* __restrict__ Whh,
                         const float* __restrict__ bhh, float* __restrict__ hs_all, int t) {
  int tid = threadIdx.x;
  int d_local = tid & 31, p_local = tid >> 5;
  int d = blockIdx.x * 32 + d_local;       // 8 tiles x 32 = 256
  int p = blockIdx.y * 8 + p_local;        // 65 tiles x 8 >= 513
  __shared__ float hsL[8][D_];
  #pragma unroll
  for (int i = 0; i < 8; ++i) {
    int pg = blockIdx.y * 8 + i;
    hsL[i][tid] = (pg < NPAT) ? h_in[(size_t)pg * D_ + tid] : 0.f;
  }
  __syncthreads();
  if (p >= NPAT) return;
  const float* hv = hsL[p_local];
  const float* wr = Whh + (size_t)d * D_;
  const float* wz = Whh + (size_t)(D_ + d) * D_;
  const float* wn = Whh + (size_t)(2 * D_ + d) * D_;
  float ar = 0.f, az = 0.f, an = 0.f;
  #pragma unroll 4
  for (int e = 0; e < D_; e += 4) {
    float4 h4 = *(const float4*)(hv + e);
    float4 r4 = *(const float4*)(wr + e);
    float4 z4 = *(const float4*)(wz + e);
    float4 n4 = *(const float4*)(wn + e);
    ar += h4.x * r4.x + h4.y * r4.y + h4.z * r4.z + h4.w * r4.w;
    az += h4.x * z4.x + h4.y * z4.y + h4.z * z4.z + h4.w * z4.w;
    an += h4.x * n4.x + h4.y * n4.y + h4.z * n4.z + h4.w * n4.w;
  }
  const float* gxp = gx + (size_t)(p * T_ + t) * 768;
  float r = sigmoidf_(gxp[d] + bhh[d] + ar);
  float z = sigmoidf_(gxp[D_ + d] + bhh[D_ + d] + az);
  // torch GRU: n = tanh(xn + r * (h@Whh_n.T + bhh_n)) -- bhh_n INSIDE the r gate
  float n = tanhf(gxp[2 * D_ + d] + r * (an + bhh[2 * D_ + d]));
  float hn = (1.f - z) * n + z * hv[d];
  h_out[(size_t)p * D_ + d] = hn;
  hs_all[(size_t)(p * T_ + t) * D_ + d] = hn;
}

// ---------------- K4: tanh(tmp)*e_full cumsum -> encoders ----------------
__global__ void enc_kernel(const float* __restrict__ tmp, const float* __restrict__ e_full,
                           const float* __restrict__ e_nomed, float* __restrict__ enc) {
  int p = blockIdx.x, d = threadIdx.x;
  float acc = 0.f;
  for (int t = 0; t < NQ; ++t) {   // t = 0..14
    size_t vi = (size_t)(p * T_ + t) * D_ + d;
    acc += tanhf(tmp[vi]) * e_full[vi];
    enc[(size_t)(p * NQ + t) * D_ + d] = acc + e_nomed[(size_t)(p * T_ + t + 1) * D_ + d];
  }
}

// ---------------- K5: row norms ----------------
__global__ void norm_kernel(const float* __restrict__ enc, float* __restrict__ norms) {
  int row = blockIdx.x * 4 + (threadIdx.x >> 6);
  int lane = threadIdx.x & 63;
  if (row >= NROWS) return;
  const float* rp = enc + (size_t)row * D_;
  float s = 0.f;
  #pragma unroll
  for (int i = 0; i < 4; ++i) { float v = rp[lane + i * 64]; s += v * v; }
  #pragma unroll
  for (int off = 32; off > 0; off >>= 1) s += __shfl_down(s, off, 64);
  if (lane == 0) norms[row] = fmaxf(sqrtf(s), EPS_);
}

// ---------------- K6: cosine sims [NQ, NM] ----------------
__global__ void sims_kernel(const float* __restrict__ enc, const float* __restrict__ norms,
                            float* __restrict__ sims) {
  int q = blockIdx.y;
  int m = blockIdx.x * 256 + threadIdx.x;
  __shared__ float qs[D_];
  qs[threadIdx.x] = enc[(size_t)(NM + q) * D_ + threadIdx.x];
  __syncthreads();
  const float* mrow = enc + (size_t)m * D_;
  float dot = 0.f;
  #pragma unroll 8
  for (int e = 0; e < D_; e += 4) {
    float4 a = *(const float4*)(qs + e);
    float4 b = *(const float4*)(mrow + e);
    dot += a.x * b.x + a.y * b.y + a.z * b.z + a.w * b.w;
  }
  sims[(size_t)q * NM + m] = dot / (norms[NM + q] * norms[m]);
}

// ---------------- K7: threshold-first top-k + weighted gather ----------------
#define CAP 4096
__global__ void topk_gather(const float* __restrict__ sims, const float* __restrict__ enc,
                            const int* __restrict__ kptr, float* __restrict__ outq) {
  int q = blockIdx.x, tid = threadIdx.x;
  __shared__ int cnt;
  __shared__ float cv[CAP];
  __shared__ int ci[CAP];
  __shared__ float selv[64];
  __shared__ int seli[64];
  __shared__ float rv[256];
  __shared__ int ri[256];
  if (tid == 0) cnt = 0;
  __syncthreads();
  const float* sq = sims + (size_t)q * NM;
  for (int j = tid; j < NM; j += 256) {
    float v = sq[j];
    if (v > THRESH_) {
      int slot = atomicAdd(&cnt, 1);
      if (slot < CAP) { cv[slot] = v; ci[slot] = j; }
    }
  }
  __syncthreads();
  int k = kptr[0];
  if (k > 64) k = 64;
  if (k < 0) k = 0;
  int n = cnt; if (n > CAP) n = CAP;
  int nsel;
  if (n <= k) {   // all candidates contribute (they're all > THRESH and within top-k)
    nsel = n;
    if (tid < n) { selv[tid] = cv[tid]; seli[tid] = ci[tid]; }
  } else {        // pick k largest among candidates (tie: lower index)
    nsel = k;
    for (int it = 0; it < k; ++it) {
      float best = -3e38f; int bslot = -1;
      for (int j = tid; j < n; j += 256) {
        float v = cv[j];
        if (v > best) { best = v; bslot = j; }
        else if (v == best && bslot >= 0 && ci[j] < ci[bslot]) { bslot = j; }
      }
      rv[tid] = best; ri[tid] = bslot;
      __syncthreads();
      for (int off = 128; off > 0; off >>= 1) {
        if (tid < off) {
          float v2 = rv[tid + off]; int s2 = ri[tid + off];
          if (s2 >= 0 && (ri[tid] < 0 || v2 > rv[tid] ||
                          (v2 == rv[tid] && ci[s2] < ci[ri[tid]]))) {
            rv[tid] = v2; ri[tid] = s2;
          }
        }
        __syncthreads();
      }
      if (tid == 0) {
        int s = ri[0];
        selv[it] = rv[0]; seli[it] = ci[s];
        cv[s] = -3e38f;   // remove
      }
      __syncthreads();
    }
  }
  __syncthreads();
  float o = enc[(size_t)(NM + q) * D_ + tid];   // Q[q][d]
  for (int j = 0; j < nsel; ++j)
    o += selv[j] * enc[(size_t)seli[j] * D_ + tid];
  outq[(size_t)q * D_ + tid] = o;
}

// ---------------- K8: output projection + sigmoid ----------------
__global__ void out_kernel(const float* __restrict__ outq, const float* __restrict__ Wo,
                           const float* __restrict__ bo, float* __restrict__ out) {
  int q = blockIdx.y;
  int v = blockIdx.x * 256 + threadIdx.x;
  __shared__ float qs[D_];
  qs[threadIdx.x] = outq[(size_t)q * D_ + threadIdx.x];
  __syncthreads();
  if (v >= V2_) return;
  const float* wr = Wo + (size_t)v * D_;
  float dot = bo[v];
  #pragma unroll 8
  for (int e = 0; e < D_; e += 4) {
    float4 a = *(const float4*)(qs + e);
    float4 b = *(const float4*)(wr + e);
    dot += a.x * b.x + a.y * b.y + a.z * b.z + a.w * b.w;
  }
  out[(size_t)q * V2_ + v] = 1.f / (1.f + expf(-dot));
}

extern "C" void kernel_launch(void* const* d_in, const int* in_sizes, int n_in,
                              void* d_out, int out_size, void* d_ws, size_t ws_size,
                              hipStream_t stream) {
  const int* qd = (const int*)d_in[0];
  const int* qp = (const int*)d_in[1];
  const int* qm = (const int*)d_in[2];
  const int* md = (const int*)d_in[3];
  const int* mp = (const int*)d_in[4];
  const int* mm = (const int*)d_in[5];
  const float* emb = (const float*)d_in[6];
  const float* Wih = (const float*)d_in[7];
  const float* Whh = (const float*)d_in[8];
  const float* bih = (const float*)d_in[9];
  const float* bhh = (const float*)d_in[10];
  const float* W2  = (const float*)d_in[11];
  const float* b2  = (const float*)d_in[12];
  const float* Wo  = (const float*)d_in[13];
  const float* bo  = (const float*)d_in[14];
  const int* kptr  = (const int*)d_in[15];
  float* out = (float*)d_out;
  (void)in_sizes; (void)n_in; (void)out_size; (void)ws_size;

  char* ws = (char*)d_ws;
  size_t off = 0;
  auto alloc = [&](size_t nfloats) {
    float* pp = (float*)(ws + off);
    off += ((nfloats * sizeof(float) + 255) & ~(size_t)255);
    return pp;
  };
  float* e_full  = alloc((size_t)NV * D_);
  float* e_nomed = alloc((size_t)NV * D_);
  float* gx      = alloc((size_t)NV * 768);
  float* hs_all  = alloc((size_t)NV * D_);
  float* h_a     = alloc((size_t)NPAT * D_);
  float* h_b     = alloc((size_t)NPAT * D_);
  float* tmp     = alloc((size_t)NV * D_);
  float* enc     = alloc((size_t)NROWS * D_);
  float* norms   = alloc(NROWS);
  float* sims    = alloc((size_t)NQ * NM);
  float* outq    = alloc((size_t)NQ * D_);

  hipMemsetAsync(h_a, 0, (size_t)NPAT * D_ * sizeof(float), stream);

  embed_kernel<<<NV, 256, 0, stream>>>(qd, qp, qm, md, mp, mm, emb, e_nomed, e_full);

  gemm_nt_bias<<<dim3(768 / BN, (NV + BM - 1) / BM), 256, 0, stream>>>(
      e_full, Wih, bih, gx, NV, 768);

  float* hin = h_a; float* hout = h_b;
  for (int t = 0; t < T_; ++t) {
    gru_step<<<dim3(8, (NPAT + 7) / 8), 256, 0, stream>>>(hin, hout, gx, Whh, bhh, hs_all, t);
    float* sw = hin; hin = hout; hout = sw;
  }

  gemm_nt_bias<<<dim3(256 / BN, (NV + BM - 1) / BM), 256, 0, stream>>>(
      hs_all, W2, b2, tmp, NV, 256);

  enc_kernel<<<NPAT, 256, 0, stream>>>(tmp, e_full, e_nomed, enc);
  norm_kernel<<<(NROWS + 3) / 4, 256, 0, stream>>>(enc, norms);
  sims_kernel<<<dim3(NM / 256, NQ), 256, 0, stream>>>(enc, norms, sims);
  topk_gather<<<NQ, 256, 0, stream>>>(sims, enc, kptr, outq);
  out_kernel<<<dim3((V2_ + 255) / 256, NQ), 256, 0, stream>>>(outq, Wo, bo, out);
}

// Round 6
// 496.074 us; speedup vs baseline: 2.0631x; 2.0631x over previous
//
#include <hip/hip_runtime.h>
#include <math.h>

constexpr int V0_ = 2000, V1_ = 1500, V2_ = 500;
constexpr int D_ = 256, T_ = 16, P_ = 512;
constexpr int LD_ = 24, LP_ = 16, LM_ = 24;
constexpr int NPAT = P_ + 1;        // 513 (512 mem + 1 query)
constexpr int NV   = NPAT * T_;     // 8208 visits
constexpr int NM   = P_ * (T_ - 1); // 7680 memory rows
constexpr int NQ   = T_ - 1;        // 15 query rows
constexpr int NROWS = NPAT * NQ;    // 7695 encoder rows (M rows then Q rows)
constexpr float THRESH_ = 0.8f;
constexpr float EPS_ = 1e-6f;

__device__ __forceinline__ float sigmoidf_(float x) { return 1.0f / (1.0f + expf(-x)); }

// ---------------- K1: embedding gather-sums ----------------
__global__ void embed_kernel(const int* __restrict__ qd, const int* __restrict__ qp,
                             const int* __restrict__ qm, const int* __restrict__ md,
                             const int* __restrict__ mp, const int* __restrict__ mm,
                             const float* __restrict__ emb,
                             float* __restrict__ e_nomed, float* __restrict__ e_full) {
  int b = blockIdx.x;           // 0..NV-1
  int p = b / T_, t = b % T_;
  int tid = threadIdx.x;
  __shared__ int codes[64];
  if (tid < 64) {
    int c;
    if (tid < LD_) {
      c = (p < P_) ? md[(p * T_ + t) * LD_ + tid] : qd[t * LD_ + tid];
    } else if (tid < LD_ + LP_) {
      int i = tid - LD_;
      c = ((p < P_) ? mp[(p * T_ + t) * LP_ + i] : qp[t * LP_ + i]) + V0_;
    } else {
      int i = tid - LD_ - LP_;
      c = ((p < P_) ? mm[(p * T_ + t) * LM_ + i] : qm[t * LM_ + i]) + V0_ + V1_;
    }
    codes[tid] = c;
  }
  __syncthreads();
  float s0 = 0.f, s1 = 0.f;
  #pragma unroll 8
  for (int i = 0; i < LD_ + LP_; ++i) s0 += emb[codes[i] * D_ + tid];
  #pragma unroll 8
  for (int i = LD_ + LP_; i < 64; ++i) s1 += emb[codes[i] * D_ + tid];
  e_nomed[(size_t)b * D_ + tid] = s0;
  e_full[(size_t)b * D_ + tid]  = s0 + s1;
}

// ---------------- K2: C[M,N] = A[M,256] * B[N,256]^T + bias[N] ----------------
// 1D grid with bijective XCD swizzle (m204): each XCD gets a contiguous chunk of
// row-major tile indices -> A row-panels stay resident in one XCD's L2.
#define BM 128
#define BN 64
#define BK 32
__global__ void gemm_nt_bias(const float* __restrict__ A, const float* __restrict__ B,
                             const float* __restrict__ bias, float* __restrict__ C,
                             int M, int N, int nct) {
  const int K = 256;
  __shared__ float As[BK][BM + 4];
  __shared__ float Bs[BK][BN + 4];
  int nb = gridDim.x;
  int b = blockIdx.x;
  int q = nb >> 3, r = nb & 7;
  int xcd = b & 7, i0 = b >> 3;
  int nbb = (xcd < r) ? (xcd * (q + 1) + i0) : (r * (q + 1) + (xcd - r) * q + i0);
  int rt = nbb / nct, ct = nbb - rt * nct;
  int r0 = rt * BM;
  int c0 = ct * BN;
  int tid = threadIdx.x;
  int tx = tid & 15, ty = tid >> 4;
  float acc[8][4];
  #pragma unroll
  for (int i = 0; i < 8; ++i)
    #pragma unroll
    for (int j = 0; j < 4; ++j) acc[i][j] = 0.f;

  for (int k0 = 0; k0 < K; k0 += BK) {
    #pragma unroll
    for (int i = 0; i < 4; ++i) {           // A tile 128x32
      int flat = i * 256 + tid;             // one float4 each
      int rr = flat >> 3;
      int kq = flat & 7;
      float4 v = make_float4(0.f, 0.f, 0.f, 0.f);
      if (r0 + rr < M) v = *(const float4*)(A + (size_t)(r0 + rr) * K + k0 + kq * 4);
      As[kq * 4 + 0][rr] = v.x; As[kq * 4 + 1][rr] = v.y;
      As[kq * 4 + 2][rr] = v.z; As[kq * 4 + 3][rr] = v.w;
    }
    #pragma unroll
    for (int i = 0; i < 2; ++i) {           // B tile 64x32 (N%64==0, no guard)
      int flat = i * 256 + tid;
      int rr = flat >> 3;
      int kq = flat & 7;
      float4 v = *(const float4*)(B + (size_t)(c0 + rr) * K + k0 + kq * 4);
      Bs[kq * 4 + 0][rr] = v.x; Bs[kq * 4 + 1][rr] = v.y;
      Bs[kq * 4 + 2][rr] = v.z; Bs[kq * 4 + 3][rr] = v.w;
    }
    __syncthreads();
    #pragma unroll
    for (int kk = 0; kk < BK; ++kk) {
      float4 a0 = *(const float4*)&As[kk][ty * 8];
      float4 a1 = *(const float4*)&As[kk][ty * 8 + 4];
      float4 bv = *(const float4*)&Bs[kk][tx * 4];
      float av[8] = {a0.x, a0.y, a0.z, a0.w, a1.x, a1.y, a1.z, a1.w};
      float bw[4] = {bv.x, bv.y, bv.z, bv.w};
      #pragma unroll
      for (int i = 0; i < 8; ++i)
        #pragma unroll
        for (int j = 0; j < 4; ++j) acc[i][j] = fmaf(av[i], bw[j], acc[i][j]);
    }
    __syncthreads();
  }
  float bv0 = bias[c0 + tx * 4 + 0], bv1 = bias[c0 + tx * 4 + 1];
  float bv2 = bias[c0 + tx * 4 + 2], bv3 = bias[c0 + tx * 4 + 3];
  #pragma unroll
  for (int i = 0; i < 8; ++i) {
    int rr = r0 + ty * 8 + i;
    if (rr < M) {
      float4 o = make_float4(acc[i][0] + bv0, acc[i][1] + bv1,
                             acc[i][2] + bv2, acc[i][3] + bv3);
      *(float4*)(C + (size_t)rr * N + c0 + tx * 4) = o;
    }
  }
}

// ---------------- K2b: Whh [768][256] -> WhhT [256][768] ----------------
__global__ void transpose_whh(const float* __restrict__ Whh, float* __restrict__ WT) {
  int idx = blockIdx.x * 256 + threadIdx.x;   // 0 .. 768*256-1
  int row = idx >> 8;       // 0..767
  int e = idx & 255;        // 0..255
  WT[e * 768 + row] = Whh[idx];
}

// ---------------- K3: one GRU step, coalesced via WhhT ----------------
// 171 blocks x 256 threads; block owns 3 patients (171*3 = 513 exactly).
// Thread d accumulates r/z/n pre-activations for 3 patients; WhhT loads are
// dword-coalesced across lanes; h broadcast from LDS.
__global__ void gru_step2(const float* __restrict__ h_in, float* __restrict__ h_out,
                          const float* __restrict__ gx, const float* __restrict__ WT,
                          const float* __restrict__ bhh, float* __restrict__ hs_all, int t) {
  int d = threadIdx.x;
  int p0 = blockIdx.x * 3;
  __shared__ float hL[3][D_];
  #pragma unroll
  for (int i = 0; i < 3; ++i) hL[i][d] = h_in[(size_t)(p0 + i) * D_ + d];
  __syncthreads();
  float ar[3] = {0.f, 0.f, 0.f}, az[3] = {0.f, 0.f, 0.f}, an[3] = {0.f, 0.f, 0.f};
  const float* wt = WT + d;
  #pragma unroll 4
  for (int e = 0; e < D_; ++e) {
    const float* we = wt + e * 768;
    float w0 = we[0];
    float w1 = we[256];
    float w2 = we[512];
    #pragma unroll
    for (int i = 0; i < 3; ++i) {
      float hv = hL[i][e];
      ar[i] = fmaf(hv, w0, ar[i]);
      az[i] = fmaf(hv, w1, az[i]);
      an[i] = fmaf(hv, w2, an[i]);
    }
  }
  float brd = bhh[d], bzd = bhh[D_ + d], bnd = bhh[2 * D_ + d];
  #pragma unroll
  for (int i = 0; i < 3; ++i) {
    int p = p0 + i;
    const float* gxp = gx + (size_t)(p * T_ + t) * 768;
    float r = sigmoidf_(gxp[d] + brd + ar[i]);
    float z = sigmoidf_(gxp[D_ + d] + bzd + az[i]);
    // torch GRU: n = tanh(xn + r * (h@Whh_n.T + bhh_n)) -- bhh_n INSIDE the r gate
    float n = tanhf(gxp[2 * D_ + d] + r * (an[i] + bnd));
    float hn = (1.f - z) * n + z * hL[i][d];
    h_out[(size_t)p * D_ + d] = hn;
    hs_all[(size_t)(p * T_ + t) * D_ + d] = hn;
  }
}

// ---------------- K4: tanh(tmp)*e_full cumsum -> encoders ----------------
__global__ void enc_kernel(const float* __restrict__ tmp, const float* __restrict__ e_full,
                           const float* __restrict__ e_nomed, float* __restrict__ enc) {
  int p = blockIdx.x, d = threadIdx.x;
  float acc = 0.f;
  for (int t = 0; t < NQ; ++t) {   // t = 0..14
    size_t vi = (size_t)(p * T_ + t) * D_ + d;
    acc += tanhf(tmp[vi]) * e_full[vi];
    enc[(size_t)(p * NQ + t) * D_ + d] = acc + e_nomed[(size_t)(p * T_ + t + 1) * D_ + d];
  }
}

// ---------------- K5: row norms ----------------
__global__ void norm_kernel(const float* __restrict__ enc, float* __restrict__ norms) {
  int row = blockIdx.x * 4 + (threadIdx.x >> 6);
  int lane = threadIdx.x & 63;
  if (row >= NROWS) return;
  const float* rp = enc + (size_t)row * D_;
  float s = 0.f;
  #pragma unroll
  for (int i = 0; i < 4; ++i) { float v = rp[lane + i * 64]; s += v * v; }
  #pragma unroll
  for (int off = 32; off > 0; off >>= 1) s += __shfl_down(s, off, 64);
  if (lane == 0) norms[row] = fmaxf(sqrtf(s), EPS_);
}

// ---------------- K6: cosine sims [NQ, NM] ----------------
__global__ void sims_kernel(const float* __restrict__ enc, const float* __restrict__ norms,
                            float* __restrict__ sims) {
  int q = blockIdx.y;
  int m = blockIdx.x * 256 + threadIdx.x;
  __shared__ float qs[D_];
  qs[threadIdx.x] = enc[(size_t)(NM + q) * D_ + threadIdx.x];
  __syncthreads();
  const float* mrow = enc + (size_t)m * D_;
  float dot = 0.f;
  #pragma unroll 8
  for (int e = 0; e < D_; e += 4) {
    float4 a = *(const float4*)(qs + e);
    float4 b = *(const float4*)(mrow + e);
    dot += a.x * b.x + a.y * b.y + a.z * b.z + a.w * b.w;
  }
  sims[(size_t)q * NM + m] = dot / (norms[NM + q] * norms[m]);
}

// ---------------- K7: threshold-first top-k + weighted gather ----------------
#define CAP 4096
__global__ void topk_gather(const float* __restrict__ sims, const float* __restrict__ enc,
                            const int* __restrict__ kptr, float* __restrict__ outq) {
  int q = blockIdx.x, tid = threadIdx.x;
  __shared__ int cnt;
  __shared__ float cv[CAP];
  __shared__ int ci[CAP];
  __shared__ float selv[64];
  __shared__ int seli[64];
  __shared__ float rv[256];
  __shared__ int ri[256];
  if (tid == 0) cnt = 0;
  __syncthreads();
  const float* sq = sims + (size_t)q * NM;
  for (int j = tid; j < NM; j += 256) {
    float v = sq[j];
    if (v > THRESH_) {
      int slot = atomicAdd(&cnt, 1);
      if (slot < CAP) { cv[slot] = v; ci[slot] = j; }
    }
  }
  __syncthreads();
  int k = kptr[0];
  if (k > 64) k = 64;
  if (k < 0) k = 0;
  int n = cnt; if (n > CAP) n = CAP;
  int nsel;
  if (n <= k) {   // all candidates contribute (they're all > THRESH and within top-k)
    nsel = n;
    if (tid < n) { selv[tid] = cv[tid]; seli[tid] = ci[tid]; }
  } else {        // pick k largest among candidates (tie: lower index)
    nsel = k;
    for (int it = 0; it < k; ++it) {
      float best = -3e38f; int bslot = -1;
      for (int j = tid; j < n; j += 256) {
        float v = cv[j];
        if (v > best) { best = v; bslot = j; }
        else if (v == best && bslot >= 0 && ci[j] < ci[bslot]) { bslot = j; }
      }
      rv[tid] = best; ri[tid] = bslot;
      __syncthreads();
      for (int off = 128; off > 0; off >>= 1) {
        if (tid < off) {
          float v2 = rv[tid + off]; int s2 = ri[tid + off];
          if (s2 >= 0 && (ri[tid] < 0 || v2 > rv[tid] ||
                          (v2 == rv[tid] && ci[s2] < ci[ri[tid]]))) {
            rv[tid] = v2; ri[tid] = s2;
          }
        }
        __syncthreads();
      }
      if (tid == 0) {
        int s = ri[0];
        selv[it] = rv[0]; seli[it] = ci[s];
        cv[s] = -3e38f;   // remove
      }
      __syncthreads();
    }
  }
  __syncthreads();
  float o = enc[(size_t)(NM + q) * D_ + tid];   // Q[q][d]
  for (int j = 0; j < nsel; ++j)
    o += selv[j] * enc[(size_t)seli[j] * D_ + tid];
  outq[(size_t)q * D_ + tid] = o;
}

// ---------------- K8: output projection + sigmoid ----------------
__global__ void out_kernel(const float* __restrict__ outq, const float* __restrict__ Wo,
                           const float* __restrict__ bo, float* __restrict__ out) {
  int q = blockIdx.y;
  int v = blockIdx.x * 256 + threadIdx.x;
  __shared__ float qs[D_];
  qs[threadIdx.x] = outq[(size_t)q * D_ + threadIdx.x];
  __syncthreads();
  if (v >= V2_) return;
  const float* wr = Wo + (size_t)v * D_;
  float dot = bo[v];
  #pragma unroll 8
  for (int e = 0; e < D_; e += 4) {
    float4 a = *(const float4*)(qs + e);
    float4 b = *(const float4*)(wr + e);
    dot += a.x * b.x + a.y * b.y + a.z * b.z + a.w * b.w;
  }
  out[(size_t)q * V2_ + v] = 1.f / (1.f + expf(-dot));
}

extern "C" void kernel_launch(void* const* d_in, const int* in_sizes, int n_in,
                              void* d_out, int out_size, void* d_ws, size_t ws_size,
                              hipStream_t stream) {
  const int* qd = (const int*)d_in[0];
  const int* qp = (const int*)d_in[1];
  const int* qm = (const int*)d_in[2];
  const int* md = (const int*)d_in[3];
  const int* mp = (const int*)d_in[4];
  const int* mm = (const int*)d_in[5];
  const float* emb = (const float*)d_in[6];
  const float* Wih = (const float*)d_in[7];
  const float* Whh = (const float*)d_in[8];
  const float* bih = (const float*)d_in[9];
  const float* bhh = (const float*)d_in[10];
  const float* W2  = (const float*)d_in[11];
  const float* b2  = (const float*)d_in[12];
  const float* Wo  = (const float*)d_in[13];
  const float* bo  = (const float*)d_in[14];
  const int* kptr  = (const int*)d_in[15];
  float* out = (float*)d_out;
  (void)in_sizes; (void)n_in; (void)out_size; (void)ws_size;

  char* ws = (char*)d_ws;
  size_t off = 0;
  auto alloc = [&](size_t nfloats) {
    float* pp = (float*)(ws + off);
    off += ((nfloats * sizeof(float) + 255) & ~(size_t)255);
    return pp;
  };
  float* e_full  = alloc((size_t)NV * D_);
  float* e_nomed = alloc((size_t)NV * D_);
  float* gx      = alloc((size_t)NV * 768);
  float* hs_all  = alloc((size_t)NV * D_);
  float* h_a     = alloc((size_t)NPAT * D_);
  float* h_b     = alloc((size_t)NPAT * D_);
  float* tmp     = alloc((size_t)NV * D_);
  float* enc     = alloc((size_t)NROWS * D_);
  float* norms   = alloc(NROWS);
  float* sims    = alloc((size_t)NQ * NM);
  float* outq    = alloc((size_t)NQ * D_);
  float* WT      = alloc((size_t)256 * 768);

  hipMemsetAsync(h_a, 0, (size_t)NPAT * D_ * sizeof(float), stream);

  embed_kernel<<<NV, 256, 0, stream>>>(qd, qp, qm, md, mp, mm, emb, e_nomed, e_full);

  transpose_whh<<<768, 256, 0, stream>>>(Whh, WT);

  {
    int nrt = (NV + BM - 1) / BM, nct = 768 / BN;
    gemm_nt_bias<<<nrt * nct, 256, 0, stream>>>(e_full, Wih, bih, gx, NV, 768, nct);
  }

  float* hin = h_a; float* hout = h_b;
  for (int t = 0; t < T_; ++t) {
    gru_step2<<<NPAT / 3, 256, 0, stream>>>(hin, hout, gx, WT, bhh, hs_all, t);
    float* sw = hin; hin = hout; hout = sw;
  }

  {
    int nrt = (NV + BM - 1) / BM, nct = 256 / BN;
    gemm_nt_bias<<<nrt * nct, 256, 0, stream>>>(hs_all, W2, b2, tmp, NV, 256, nct);
  }

  enc_kernel<<<NPAT, 256, 0, stream>>>(tmp, e_full, e_nomed, enc);
  norm_kernel<<<(NROWS + 3) / 4, 256, 0, stream>>>(enc, norms);
  sims_kernel<<<dim3(NM / 256, NQ), 256, 0, stream>>>(enc, norms, sims);
  topk_gather<<<NQ, 256, 0, stream>>>(sims, enc, kptr, outq);
  out_kernel<<<dim3((V2_ + 255) / 256, NQ), 256, 0, stream>>>(outq, Wo, bo, out);
}

// Round 7
// 408.470 us; speedup vs baseline: 2.5056x; 1.2145x over previous
//
#include <hip/hip_runtime.h>
#include <math.h>

constexpr int V0_ = 2000, V1_ = 1500, V2_ = 500;
constexpr int D_ = 256, T_ = 16, P_ = 512;
constexpr int LD_ = 24, LP_ = 16, LM_ = 24;
constexpr int NPAT = P_ + 1;        // 513 (512 mem + 1 query)
constexpr int NV   = NPAT * T_;     // 8208 visits
constexpr int NM   = P_ * (T_ - 1); // 7680 memory rows
constexpr int NQ   = T_ - 1;        // 15 query rows
constexpr int NROWS = NPAT * NQ;    // 7695 encoder rows (M rows then Q rows)
constexpr float THRESH_ = 0.8f;
constexpr float EPS_ = 1e-6f;

__device__ __forceinline__ float sigmoidf_(float x) { return 1.0f / (1.0f + expf(-x)); }

// ---------------- K1: embedding gather-sums ----------------
__global__ void embed_kernel(const int* __restrict__ qd, const int* __restrict__ qp,
                             const int* __restrict__ qm, const int* __restrict__ md,
                             const int* __restrict__ mp, const int* __restrict__ mm,
                             const float* __restrict__ emb,
                             float* __restrict__ e_nomed, float* __restrict__ e_full) {
  int b = blockIdx.x;           // 0..NV-1
  int p = b / T_, t = b % T_;
  int tid = threadIdx.x;
  __shared__ int codes[64];
  if (tid < 64) {
    int c;
    if (tid < LD_) {
      c = (p < P_) ? md[(p * T_ + t) * LD_ + tid] : qd[t * LD_ + tid];
    } else if (tid < LD_ + LP_) {
      int i = tid - LD_;
      c = ((p < P_) ? mp[(p * T_ + t) * LP_ + i] : qp[t * LP_ + i]) + V0_;
    } else {
      int i = tid - LD_ - LP_;
      c = ((p < P_) ? mm[(p * T_ + t) * LM_ + i] : qm[t * LM_ + i]) + V0_ + V1_;
    }
    codes[tid] = c;
  }
  __syncthreads();
  float s0 = 0.f, s1 = 0.f;
  #pragma unroll 8
  for (int i = 0; i < LD_ + LP_; ++i) s0 += emb[codes[i] * D_ + tid];
  #pragma unroll 8
  for (int i = LD_ + LP_; i < 64; ++i) s1 += emb[codes[i] * D_ + tid];
  e_nomed[(size_t)b * D_ + tid] = s0;
  e_full[(size_t)b * D_ + tid]  = s0 + s1;
}

// ---------------- K2: C[M,N] = A[M,256] * B[N,256]^T + bias[N] ----------------
// 1D grid with bijective XCD swizzle; LDS pads +5 so staging stores hit
// distinct bank octets per kq (was +4 -> 4-way write conflicts, 3.59M/dispatch).
#define BM 128
#define BN 64
#define BK 32
__global__ void gemm_nt_bias(const float* __restrict__ A, const float* __restrict__ B,
                             const float* __restrict__ bias, float* __restrict__ C,
                             int M, int N, int nct) {
  const int K = 256;
  __shared__ float As[BK][BM + 5];
  __shared__ float Bs[BK][BN + 5];
  int nb = gridDim.x;
  int b = blockIdx.x;
  int q = nb >> 3, r = nb & 7;
  int xcd = b & 7, i0 = b >> 3;
  int nbb = (xcd < r) ? (xcd * (q + 1) + i0) : (r * (q + 1) + (xcd - r) * q + i0);
  int rt = nbb / nct, ct = nbb - rt * nct;
  int r0 = rt * BM;
  int c0 = ct * BN;
  int tid = threadIdx.x;
  int tx = tid & 15, ty = tid >> 4;
  float acc[8][4];
  #pragma unroll
  for (int i = 0; i < 8; ++i)
    #pragma unroll
    for (int j = 0; j < 4; ++j) acc[i][j] = 0.f;

  for (int k0 = 0; k0 < K; k0 += BK) {
    #pragma unroll
    for (int i = 0; i < 4; ++i) {           // A tile 128x32
      int flat = i * 256 + tid;             // one float4 each
      int rr = flat >> 3;
      int kq = flat & 7;
      float4 v = make_float4(0.f, 0.f, 0.f, 0.f);
      if (r0 + rr < M) v = *(const float4*)(A + (size_t)(r0 + rr) * K + k0 + kq * 4);
      As[kq * 4 + 0][rr] = v.x; As[kq * 4 + 1][rr] = v.y;
      As[kq * 4 + 2][rr] = v.z; As[kq * 4 + 3][rr] = v.w;
    }
    #pragma unroll
    for (int i = 0; i < 2; ++i) {           // B tile 64x32 (N%64==0, no guard)
      int flat = i * 256 + tid;
      int rr = flat >> 3;
      int kq = flat & 7;
      float4 v = *(const float4*)(B + (size_t)(c0 + rr) * K + k0 + kq * 4);
      Bs[kq * 4 + 0][rr] = v.x; Bs[kq * 4 + 1][rr] = v.y;
      Bs[kq * 4 + 2][rr] = v.z; Bs[kq * 4 + 3][rr] = v.w;
    }
    __syncthreads();
    #pragma unroll
    for (int kk = 0; kk < BK; ++kk) {
      float4 a0 = *(const float4*)&As[kk][ty * 8];
      float4 a1 = *(const float4*)&As[kk][ty * 8 + 4];
      float4 bv = *(const float4*)&Bs[kk][tx * 4];
      float av[8] = {a0.x, a0.y, a0.z, a0.w, a1.x, a1.y, a1.z, a1.w};
      float bw[4] = {bv.x, bv.y, bv.z, bv.w};
      #pragma unroll
      for (int i = 0; i < 8; ++i)
        #pragma unroll
        for (int j = 0; j < 4; ++j) acc[i][j] = fmaf(av[i], bw[j], acc[i][j]);
    }
    __syncthreads();
  }
  float bv0 = bias[c0 + tx * 4 + 0], bv1 = bias[c0 + tx * 4 + 1];
  float bv2 = bias[c0 + tx * 4 + 2], bv3 = bias[c0 + tx * 4 + 3];
  #pragma unroll
  for (int i = 0; i < 8; ++i) {
    int rr = r0 + ty * 8 + i;
    if (rr < M) {
      float4 o = make_float4(acc[i][0] + bv0, acc[i][1] + bv1,
                             acc[i][2] + bv2, acc[i][3] + bv3);
      *(float4*)(C + (size_t)rr * N + c0 + tx * 4) = o;
    }
  }
}

// ---------------- K2b: Whh [768][256] -> WhhT [256][768] ----------------
__global__ void transpose_whh(const float* __restrict__ Whh, float* __restrict__ WT) {
  int idx = blockIdx.x * 256 + threadIdx.x;   // 0 .. 768*256-1
  int row = idx >> 8;       // 0..767
  int e = idx & 255;        // 0..255
  WT[e * 768 + row] = Whh[idx];
}

// ---------------- K3: persistent GRU -- all 16 steps in one launch ----------------
// 171 blocks x 512 threads. Block owns 3 patients (171*3=513): the recurrence
// for a patient needs only its own h, so no cross-block sync across time.
// Threads: d = tid&255 (output dim), h = tid>>8 (e-range half). h kept in LDS
// for all steps; half 1's partial dot-products reduced via LDS.
__global__ __launch_bounds__(512) void gru_all(const float* __restrict__ gx,
                                               const float* __restrict__ WT,
                                               const float* __restrict__ bhh,
                                               float* __restrict__ hs_all) {
  int tid = threadIdx.x;
  int d = tid & 255;
  int hf = tid >> 8;          // 0 or 1
  int p0 = blockIdx.x * 3;
  __shared__ float hL[3][D_];
  __shared__ float part[9][D_];
  if (hf == 0) { hL[0][d] = 0.f; hL[1][d] = 0.f; hL[2][d] = 0.f; }
  float brd = bhh[d], bzd = bhh[D_ + d], bnd = bhh[2 * D_ + d];
  __syncthreads();

  for (int t = 0; t < T_; ++t) {
    float ar[3] = {0.f, 0.f, 0.f}, az[3] = {0.f, 0.f, 0.f}, an[3] = {0.f, 0.f, 0.f};
    const float* wt = WT + d;
    int e0 = hf << 7;
    #pragma unroll 4
    for (int e = e0; e < e0 + 128; ++e) {
      const float* we = wt + (size_t)e * 768;
      float w0 = we[0];
      float w1 = we[256];
      float w2 = we[512];
      float h0 = hL[0][e], h1 = hL[1][e], h2 = hL[2][e];
      ar[0] = fmaf(h0, w0, ar[0]); az[0] = fmaf(h0, w1, az[0]); an[0] = fmaf(h0, w2, an[0]);
      ar[1] = fmaf(h1, w0, ar[1]); az[1] = fmaf(h1, w1, az[1]); an[1] = fmaf(h1, w2, an[1]);
      ar[2] = fmaf(h2, w0, ar[2]); az[2] = fmaf(h2, w1, az[2]); an[2] = fmaf(h2, w2, an[2]);
    }
    if (hf == 1) {
      #pragma unroll
      for (int i = 0; i < 3; ++i) {
        part[i][d] = ar[i]; part[3 + i][d] = az[i]; part[6 + i][d] = an[i];
      }
    }
    __syncthreads();
    if (hf == 0) {
      #pragma unroll
      for (int i = 0; i < 3; ++i) {
        int p = p0 + i;
        const float* gxp = gx + (size_t)(p * T_ + t) * 768;
        float r = sigmoidf_(gxp[d] + brd + ar[i] + part[i][d]);
        float z = sigmoidf_(gxp[D_ + d] + bzd + az[i] + part[3 + i][d]);
        // torch GRU: n = tanh(xn + r*(h@Whh_n.T + bhh_n)) -- bhh_n INSIDE r gate
        float n = tanhf(gxp[2 * D_ + d] + r * (an[i] + part[6 + i][d] + bnd));
        float hn = (1.f - z) * n + z * hL[i][d];
        hL[i][d] = hn;
        hs_all[(size_t)(p * T_ + t) * D_ + d] = hn;
      }
    }
    __syncthreads();
  }
}

// ---------------- K4: tanh(tmp)*e_full cumsum -> encoders ----------------
__global__ void enc_kernel(const float* __restrict__ tmp, const float* __restrict__ e_full,
                           const float* __restrict__ e_nomed, float* __restrict__ enc) {
  int p = blockIdx.x, d = threadIdx.x;
  float acc = 0.f;
  for (int t = 0; t < NQ; ++t) {   // t = 0..14
    size_t vi = (size_t)(p * T_ + t) * D_ + d;
    acc += tanhf(tmp[vi]) * e_full[vi];
    enc[(size_t)(p * NQ + t) * D_ + d] = acc + e_nomed[(size_t)(p * T_ + t + 1) * D_ + d];
  }
}

// ---------------- K5: row norms ----------------
__global__ void norm_kernel(const float* __restrict__ enc, float* __restrict__ norms) {
  int row = blockIdx.x * 4 + (threadIdx.x >> 6);
  int lane = threadIdx.x & 63;
  if (row >= NROWS) return;
  const float* rp = enc + (size_t)row * D_;
  float s = 0.f;
  #pragma unroll
  for (int i = 0; i < 4; ++i) { float v = rp[lane + i * 64]; s += v * v; }
  #pragma unroll
  for (int off = 32; off > 0; off >>= 1) s += __shfl_down(s, off, 64);
  if (lane == 0) norms[row] = fmaxf(sqrtf(s), EPS_);
}

// ---------------- K6: cosine sims [NQ, NM] ----------------
__global__ void sims_kernel(const float* __restrict__ enc, const float* __restrict__ norms,
                            float* __restrict__ sims) {
  int q = blockIdx.y;
  int m = blockIdx.x * 256 + threadIdx.x;
  __shared__ float qs[D_];
  qs[threadIdx.x] = enc[(size_t)(NM + q) * D_ + threadIdx.x];
  __syncthreads();
  const float* mrow = enc + (size_t)m * D_;
  float dot = 0.f;
  #pragma unroll 8
  for (int e = 0; e < D_; e += 4) {
    float4 a = *(const float4*)(qs + e);
    float4 b = *(const float4*)(mrow + e);
    dot += a.x * b.x + a.y * b.y + a.z * b.z + a.w * b.w;
  }
  sims[(size_t)q * NM + m] = dot / (norms[NM + q] * norms[m]);
}

// ---------------- K7: threshold-first top-k + weighted gather ----------------
#define CAP 4096
__global__ void topk_gather(const float* __restrict__ sims, const float* __restrict__ enc,
                            const int* __restrict__ kptr, float* __restrict__ outq) {
  int q = blockIdx.x, tid = threadIdx.x;
  __shared__ int cnt;
  __shared__ float cv[CAP];
  __shared__ int ci[CAP];
  __shared__ float selv[64];
  __shared__ int seli[64];
  __shared__ float rv[256];
  __shared__ int ri[256];
  if (tid == 0) cnt = 0;
  __syncthreads();
  const float* sq = sims + (size_t)q * NM;
  for (int j = tid; j < NM; j += 256) {
    float v = sq[j];
    if (v > THRESH_) {
      int slot = atomicAdd(&cnt, 1);
      if (slot < CAP) { cv[slot] = v; ci[slot] = j; }
    }
  }
  __syncthreads();
  int k = kptr[0];
  if (k > 64) k = 64;
  if (k < 0) k = 0;
  int n = cnt; if (n > CAP) n = CAP;
  int nsel;
  if (n <= k) {   // all candidates contribute (they're all > THRESH and within top-k)
    nsel = n;
    if (tid < n) { selv[tid] = cv[tid]; seli[tid] = ci[tid]; }
  } else {        // pick k largest among candidates (tie: lower index)
    nsel = k;
    for (int it = 0; it < k; ++it) {
      float best = -3e38f; int bslot = -1;
      for (int j = tid; j < n; j += 256) {
        float v = cv[j];
        if (v > best) { best = v; bslot = j; }
        else if (v == best && bslot >= 0 && ci[j] < ci[bslot]) { bslot = j; }
      }
      rv[tid] = best; ri[tid] = bslot;
      __syncthreads();
      for (int off = 128; off > 0; off >>= 1) {
        if (tid < off) {
          float v2 = rv[tid + off]; int s2 = ri[tid + off];
          if (s2 >= 0 && (ri[tid] < 0 || v2 > rv[tid] ||
                          (v2 == rv[tid] && ci[s2] < ci[ri[tid]]))) {
            rv[tid] = v2; ri[tid] = s2;
          }
        }
        __syncthreads();
      }
      if (tid == 0) {
        int s = ri[0];
        selv[it] = rv[0]; seli[it] = ci[s];
        cv[s] = -3e38f;   // remove
      }
      __syncthreads();
    }
  }
  __syncthreads();
  float o = enc[(size_t)(NM + q) * D_ + tid];   // Q[q][d]
  for (int j = 0; j < nsel; ++j)
    o += selv[j] * enc[(size_t)seli[j] * D_ + tid];
  outq[(size_t)q * D_ + tid] = o;
}

// ---------------- K8: output projection + sigmoid ----------------
__global__ void out_kernel(const float* __restrict__ outq, const float* __restrict__ Wo,
                           const float* __restrict__ bo, float* __restrict__ out) {
  int q = blockIdx.y;
  int v = blockIdx.x * 256 + threadIdx.x;
  __shared__ float qs[D_];
  qs[threadIdx.x] = outq[(size_t)q * D_ + threadIdx.x];
  __syncthreads();
  if (v >= V2_) return;
  const float* wr = Wo + (size_t)v * D_;
  float dot = bo[v];
  #pragma unroll 8
  for (int e = 0; e < D_; e += 4) {
    float4 a = *(const float4*)(qs + e);
    float4 b = *(const float4*)(wr + e);
    dot += a.x * b.x + a.y * b.y + a.z * b.z + a.w * b.w;
  }
  out[(size_t)q * V2_ + v] = 1.f / (1.f + expf(-dot));
}

extern "C" void kernel_launch(void* const* d_in, const int* in_sizes, int n_in,
                              void* d_out, int out_size, void* d_ws, size_t ws_size,
                              hipStream_t stream) {
  const int* qd = (const int*)d_in[0];
  const int* qp = (const int*)d_in[1];
  const int* qm = (const int*)d_in[2];
  const int* md = (const int*)d_in[3];
  const int* mp = (const int*)d_in[4];
  const int* mm = (const int*)d_in[5];
  const float* emb = (const float*)d_in[6];
  const float* Wih = (const float*)d_in[7];
  const float* Whh = (const float*)d_in[8];
  const float* bih = (const float*)d_in[9];
  const float* bhh = (const float*)d_in[10];
  const float* W2  = (const float*)d_in[11];
  const float* b2  = (const float*)d_in[12];
  const float* Wo  = (const float*)d_in[13];
  const float* bo  = (const float*)d_in[14];
  const int* kptr  = (const int*)d_in[15];
  float* out = (float*)d_out;
  (void)in_sizes; (void)n_in; (void)out_size; (void)ws_size;

  char* ws = (char*)d_ws;
  size_t off = 0;
  auto alloc = [&](size_t nfloats) {
    float* pp = (float*)(ws + off);
    off += ((nfloats * sizeof(float) + 255) & ~(size_t)255);
    return pp;
  };
  float* e_full  = alloc((size_t)NV * D_);
  float* e_nomed = alloc((size_t)NV * D_);
  float* gx      = alloc((size_t)NV * 768);
  float* hs_all  = alloc((size_t)NV * D_);
  float* tmp     = alloc((size_t)NV * D_);
  float* enc     = alloc((size_t)NROWS * D_);
  float* norms   = alloc(NROWS);
  float* sims    = alloc((size_t)NQ * NM);
  float* outq    = alloc((size_t)NQ * D_);
  float* WT      = alloc((size_t)256 * 768);

  embed_kernel<<<NV, 256, 0, stream>>>(qd, qp, qm, md, mp, mm, emb, e_nomed, e_full);

  transpose_whh<<<768, 256, 0, stream>>>(Whh, WT);

  {
    int nrt = (NV + BM - 1) / BM, nct = 768 / BN;
    gemm_nt_bias<<<nrt * nct, 256, 0, stream>>>(e_full, Wih, bih, gx, NV, 768, nct);
  }

  gru_all<<<NPAT / 3, 512, 0, stream>>>(gx, WT, bhh, hs_all);

  {
    int nrt = (NV + BM - 1) / BM, nct = 256 / BN;
    gemm_nt_bias<<<nrt * nct, 256, 0, stream>>>(hs_all, W2, b2, tmp, NV, 256, nct);
  }

  enc_kernel<<<NPAT, 256, 0, stream>>>(tmp, e_full, e_nomed, enc);
  norm_kernel<<<(NROWS + 3) / 4, 256, 0, stream>>>(enc, norms);
  sims_kernel<<<dim3(NM / 256, NQ), 256, 0, stream>>>(enc, norms, sims);
  topk_gather<<<NQ, 256, 0, stream>>>(sims, enc, kptr, outq);
  out_kernel<<<dim3((V2_ + 255) / 256, NQ), 256, 0, stream>>>(outq, Wo, bo, out);
}

// Round 9
// 387.879 us; speedup vs baseline: 2.6386x; 1.0531x over previous
//
#include <hip/hip_runtime.h>
#include <math.h>

constexpr int V0_ = 2000, V1_ = 1500, V2_ = 500;
constexpr int D_ = 256, T_ = 16, P_ = 512;
constexpr int LD_ = 24, LP_ = 16, LM_ = 24;
constexpr int NPAT = P_ + 1;        // 513 (512 mem + 1 query)
constexpr int NV   = NPAT * T_;     // 8208 visits
constexpr int NM   = P_ * (T_ - 1); // 7680 memory rows
constexpr int NQ   = T_ - 1;        // 15 query rows
constexpr int NROWS = NPAT * NQ;    // 7695 encoder rows (M rows then Q rows)
constexpr float THRESH_ = 0.8f;
constexpr float EPS_ = 1e-6f;

__device__ __forceinline__ float sigmoidf_(float x) { return 1.0f / (1.0f + expf(-x)); }

// ---------------- K1: embedding gather-sums ----------------
__global__ void embed_kernel(const int* __restrict__ qd, const int* __restrict__ qp,
                             const int* __restrict__ qm, const int* __restrict__ md,
                             const int* __restrict__ mp, const int* __restrict__ mm,
                             const float* __restrict__ emb,
                             float* __restrict__ e_nomed, float* __restrict__ e_full) {
  int b = blockIdx.x;           // 0..NV-1
  int p = b / T_, t = b % T_;
  int tid = threadIdx.x;
  __shared__ int codes[64];
  if (tid < 64) {
    int c;
    if (tid < LD_) {
      c = (p < P_) ? md[(p * T_ + t) * LD_ + tid] : qd[t * LD_ + tid];
    } else if (tid < LD_ + LP_) {
      int i = tid - LD_;
      c = ((p < P_) ? mp[(p * T_ + t) * LP_ + i] : qp[t * LP_ + i]) + V0_;
    } else {
      int i = tid - LD_ - LP_;
      c = ((p < P_) ? mm[(p * T_ + t) * LM_ + i] : qm[t * LM_ + i]) + V0_ + V1_;
    }
    codes[tid] = c;
  }
  __syncthreads();
  float s0 = 0.f, s1 = 0.f;
  #pragma unroll 8
  for (int i = 0; i < LD_ + LP_; ++i) s0 += emb[codes[i] * D_ + tid];
  #pragma unroll 8
  for (int i = LD_ + LP_; i < 64; ++i) s1 += emb[codes[i] * D_ + tid];
  e_nomed[(size_t)b * D_ + tid] = s0;
  e_full[(size_t)b * D_ + tid]  = s0 + s1;
}

// ---------------- K2: C[M,N] = A[M,256] * B[N,256]^T + bias[N] ----------------
#define BM 128
#define BN 64
#define BK 32
__global__ void gemm_nt_bias(const float* __restrict__ A, const float* __restrict__ B,
                             const float* __restrict__ bias, float* __restrict__ C,
                             int M, int N, int nct) {
  const int K = 256;
  __shared__ float As[BK][BM + 5];
  __shared__ float Bs[BK][BN + 5];
  int nb = gridDim.x;
  int b = blockIdx.x;
  int q = nb >> 3, r = nb & 7;
  int xcd = b & 7, i0 = b >> 3;
  int nbb = (xcd < r) ? (xcd * (q + 1) + i0) : (r * (q + 1) + (xcd - r) * q + i0);
  int rt = nbb / nct, ct = nbb - rt * nct;
  int r0 = rt * BM;
  int c0 = ct * BN;
  int tid = threadIdx.x;
  int tx = tid & 15, ty = tid >> 4;
  float acc[8][4];
  #pragma unroll
  for (int i = 0; i < 8; ++i)
    #pragma unroll
    for (int j = 0; j < 4; ++j) acc[i][j] = 0.f;

  for (int k0 = 0; k0 < K; k0 += BK) {
    #pragma unroll
    for (int i = 0; i < 4; ++i) {           // A tile 128x32
      int flat = i * 256 + tid;             // one float4 each
      int rr = flat >> 3;
      int kq = flat & 7;
      float4 v = make_float4(0.f, 0.f, 0.f, 0.f);
      if (r0 + rr < M) v = *(const float4*)(A + (size_t)(r0 + rr) * K + k0 + kq * 4);
      As[kq * 4 + 0][rr] = v.x; As[kq * 4 + 1][rr] = v.y;
      As[kq * 4 + 2][rr] = v.z; As[kq * 4 + 3][rr] = v.w;
    }
    #pragma unroll
    for (int i = 0; i < 2; ++i) {           // B tile 64x32 (N%64==0, no guard)
      int flat = i * 256 + tid;
      int rr = flat >> 3;
      int kq = flat & 7;
      float4 v = *(const float4*)(B + (size_t)(c0 + rr) * K + k0 + kq * 4);
      Bs[kq * 4 + 0][rr] = v.x; Bs[kq * 4 + 1][rr] = v.y;
      Bs[kq * 4 + 2][rr] = v.z; Bs[kq * 4 + 3][rr] = v.w;
    }
    __syncthreads();
    #pragma unroll
    for (int kk = 0; kk < BK; ++kk) {
      float4 a0 = *(const float4*)&As[kk][ty * 8];
      float4 a1 = *(const float4*)&As[kk][ty * 8 + 4];
      float4 bv = *(const float4*)&Bs[kk][tx * 4];
      float av[8] = {a0.x, a0.y, a0.z, a0.w, a1.x, a1.y, a1.z, a1.w};
      float bw[4] = {bv.x, bv.y, bv.z, bv.w};
      #pragma unroll
      for (int i = 0; i < 8; ++i)
        #pragma unroll
        for (int j = 0; j < 4; ++j) acc[i][j] = fmaf(av[i], bw[j], acc[i][j]);
    }
    __syncthreads();
  }
  float bv0 = bias[c0 + tx * 4 + 0], bv1 = bias[c0 + tx * 4 + 1];
  float bv2 = bias[c0 + tx * 4 + 2], bv3 = bias[c0 + tx * 4 + 3];
  #pragma unroll
  for (int i = 0; i < 8; ++i) {
    int rr = r0 + ty * 8 + i;
    if (rr < M) {
      float4 o = make_float4(acc[i][0] + bv0, acc[i][1] + bv1,
                             acc[i][2] + bv2, acc[i][3] + bv3);
      *(float4*)(C + (size_t)rr * N + c0 + tx * 4) = o;
    }
  }
}

// ---------------- K2b: Whh [768][256] -> WT4 [e4][gate][d][4] ----------------
// WT4 float4-index = (e4*3 + g)*256 + d ; holds Whh[(g*256+d)][e4*4 .. e4*4+3]
__global__ void transpose_whh(const float* __restrict__ Whh, float* __restrict__ WT4) {
  int b = blockIdx.x;          // 0..191 = e4*3 + g
  int e4 = b / 3, g = b - e4 * 3;
  int d = threadIdx.x;
  float4 v = *(const float4*)(Whh + ((size_t)(g * 256 + d)) * 256 + e4 * 4);
  *((float4*)WT4 + (size_t)b * 256 + d) = v;
}

// ---------------- K3: persistent GRU, float4 weights, 4-way e-split ----------------
// 171 blocks x 1024 threads; block owns 3 patients. d = tid&255, quarter
// qt = tid>>8 handles e in [qt*64, qt*64+64) as 16 float4 groups. Quarter
// partials reduced through LDS; quarter 0 applies the gates.
__global__ __launch_bounds__(1024) void gru_all(const float* __restrict__ gx,
                                                const float* __restrict__ WT4,
                                                const float* __restrict__ bhh,
                                                float* __restrict__ hs_all) {
  int tid = threadIdx.x;
  int d = tid & 255;
  int qt = tid >> 8;          // 0..3
  int p0 = blockIdx.x * 3;
  __shared__ float hL[3][D_];
  __shared__ float part[3][9][D_];
  if (qt == 0) { hL[0][d] = 0.f; hL[1][d] = 0.f; hL[2][d] = 0.f; }
  float brd = bhh[d], bzd = bhh[D_ + d], bnd = bhh[2 * D_ + d];
  __syncthreads();

  const float4* wt = (const float4*)WT4 + d;
  for (int t = 0; t < T_; ++t) {
    float ar[3] = {0.f, 0.f, 0.f}, az[3] = {0.f, 0.f, 0.f}, an[3] = {0.f, 0.f, 0.f};
    int e40 = qt << 4;
    #pragma unroll 4
    for (int e4 = e40; e4 < e40 + 16; ++e4) {
      const float4* wb = wt + (size_t)(e4 * 3) * 256;
      float4 w0 = wb[0];
      float4 w1 = wb[256];
      float4 w2 = wb[512];
      #pragma unroll
      for (int i = 0; i < 3; ++i) {
        float4 h4 = *(const float4*)&hL[i][e4 << 2];   // LDS broadcast
        ar[i] = fmaf(h4.x, w0.x, ar[i]); ar[i] = fmaf(h4.y, w0.y, ar[i]);
        ar[i] = fmaf(h4.z, w0.z, ar[i]); ar[i] = fmaf(h4.w, w0.w, ar[i]);
        az[i] = fmaf(h4.x, w1.x, az[i]); az[i] = fmaf(h4.y, w1.y, az[i]);
        az[i] = fmaf(h4.z, w1.z, az[i]); az[i] = fmaf(h4.w, w1.w, az[i]);
        an[i] = fmaf(h4.x, w2.x, an[i]); an[i] = fmaf(h4.y, w2.y, an[i]);
        an[i] = fmaf(h4.z, w2.z, an[i]); an[i] = fmaf(h4.w, w2.w, an[i]);
      }
    }
    if (qt) {
      int s = qt - 1;
      #pragma unroll
      for (int i = 0; i < 3; ++i) {
        part[s][i][d] = ar[i]; part[s][3 + i][d] = az[i]; part[s][6 + i][d] = an[i];
      }
    }
    __syncthreads();
    if (qt == 0) {
      #pragma unroll
      for (int i = 0; i < 3; ++i) {
        int p = p0 + i;
        const float* gxp = gx + (size_t)(p * T_ + t) * 768;
        float arf = ar[i] + part[0][i][d] + part[1][i][d] + part[2][i][d];
        float azf = az[i] + part[0][3 + i][d] + part[1][3 + i][d] + part[2][3 + i][d];
        float anf = an[i] + part[0][6 + i][d] + part[1][6 + i][d] + part[2][6 + i][d];
        float r = sigmoidf_(gxp[d] + brd + arf);
        float z = sigmoidf_(gxp[D_ + d] + bzd + azf);
        // torch GRU: n = tanh(xn + r*(h@Whh_n.T + bhh_n)) -- bhh_n INSIDE r gate
        float n = tanhf(gxp[2 * D_ + d] + r * (anf + bnd));
        float hn = (1.f - z) * n + z * hL[i][d];
        hL[i][d] = hn;
        hs_all[(size_t)(p * T_ + t) * D_ + d] = hn;
      }
    }
    __syncthreads();
  }
}

// ---------------- K4: tanh(tmp)*e_full cumsum -> encoders (+fused norms) ------
__global__ void enc_kernel(const float* __restrict__ tmp, const float* __restrict__ e_full,
                           const float* __restrict__ e_nomed, float* __restrict__ enc,
                           float* __restrict__ norms) {
  int p = blockIdx.x, d = threadIdx.x;
  __shared__ float red[4];
  float acc = 0.f;
  for (int t = 0; t < NQ; ++t) {   // t = 0..14
    size_t vi = (size_t)(p * T_ + t) * D_ + d;
    acc += tanhf(tmp[vi]) * e_full[vi];
    float ev = acc + e_nomed[(size_t)(p * T_ + t + 1) * D_ + d];
    int row = p * NQ + t;
    enc[(size_t)row * D_ + d] = ev;
    float s = ev * ev;
    #pragma unroll
    for (int off = 32; off > 0; off >>= 1) s += __shfl_down(s, off, 64);
    if ((d & 63) == 0) red[d >> 6] = s;
    __syncthreads();
    if (d == 0) norms[row] = fmaxf(sqrtf(red[0] + red[1] + red[2] + red[3]), EPS_);
    __syncthreads();
  }
}

// ---------------- K6: cosine sims [NQ, NM] ----------------
__global__ void sims_kernel(const float* __restrict__ enc, const float* __restrict__ norms,
                            float* __restrict__ sims) {
  int q = blockIdx.y;
  int m = blockIdx.x * 256 + threadIdx.x;
  __shared__ float qs[D_];
  qs[threadIdx.x] = enc[(size_t)(NM + q) * D_ + threadIdx.x];
  __syncthreads();
  const float* mrow = enc + (size_t)m * D_;
  float dot = 0.f;
  #pragma unroll 8
  for (int e = 0; e < D_; e += 4) {
    float4 a = *(const float4*)(qs + e);
    float4 b = *(const float4*)(mrow + e);
    dot += a.x * b.x + a.y * b.y + a.z * b.z + a.w * b.w;
  }
  sims[(size_t)q * NM + m] = dot / (norms[NM + q] * norms[m]);
}

// ---------------- K7: threshold-first top-k + weighted gather ----------------
#define CAP 4096
__global__ void topk_gather(const float* __restrict__ sims, const float* __restrict__ enc,
                            const int* __restrict__ kptr, float* __restrict__ outq) {
  int q = blockIdx.x, tid = threadIdx.x;
  __shared__ int cnt;
  __shared__ float cv[CAP];
  __shared__ int ci[CAP];
  __shared__ float selv[64];
  __shared__ int seli[64];
  __shared__ float rv[256];
  __shared__ int ri[256];
  if (tid == 0) cnt = 0;
  __syncthreads();
  const float* sq = sims + (size_t)q * NM;
  for (int j = tid; j < NM; j += 256) {
    float v = sq[j];
    if (v > THRESH_) {
      int slot = atomicAdd(&cnt, 1);
      if (slot < CAP) { cv[slot] = v; ci[slot] = j; }
    }
  }
  __syncthreads();
  int k = kptr[0];
  if (k > 64) k = 64;
  if (k < 0) k = 0;
  int n = cnt; if (n > CAP) n = CAP;
  int nsel;
  if (n <= k) {   // all candidates contribute (they're all > THRESH and within top-k)
    nsel = n;
    if (tid < n) { selv[tid] = cv[tid]; seli[tid] = ci[tid]; }
  } else {        // pick k largest among candidates (tie: lower index)
    nsel = k;
    for (int it = 0; it < k; ++it) {
      float best = -3e38f; int bslot = -1;
      for (int j = tid; j < n; j += 256) {
        float v = cv[j];
        if (v > best) { best = v; bslot = j; }
        else if (v == best && bslot >= 0 && ci[j] < ci[bslot]) { bslot = j; }
      }
      rv[tid] = best; ri[tid] = bslot;
      __syncthreads();
      for (int off = 128; off > 0; off >>= 1) {
        if (tid < off) {
          float v2 = rv[tid + off]; int s2 = ri[tid + off];
          if (s2 >= 0 && (ri[tid] < 0 || v2 > rv[tid] ||
                          (v2 == rv[tid] && ci[s2] < ci[ri[tid]]))) {
            rv[tid] = v2; ri[tid] = s2;
          }
        }
        __syncthreads();
      }
      if (tid == 0) {
        int s = ri[0];
        selv[it] = rv[0]; seli[it] = ci[s];
        cv[s] = -3e38f;   // remove
      }
      __syncthreads();
    }
  }
  __syncthreads();
  float o = enc[(size_t)(NM + q) * D_ + tid];   // Q[q][d]
  for (int j = 0; j < nsel; ++j)
    o += selv[j] * enc[(size_t)seli[j] * D_ + tid];
  outq[(size_t)q * D_ + tid] = o;
}

// ---------------- K8: output projection + sigmoid ----------------
__global__ void out_kernel(const float* __restrict__ outq, const float* __restrict__ Wo,
                           const float* __restrict__ bo, float* __restrict__ out) {
  int q = blockIdx.y;
  int v = blockIdx.x * 256 + threadIdx.x;
  __shared__ float qs[D_];
  qs[threadIdx.x] = outq[(size_t)q * D_ + threadIdx.x];
  __syncthreads();
  if (v >= V2_) return;
  const float* wr = Wo + (size_t)v * D_;
  float dot = bo[v];
  #pragma unroll 8
  for (int e = 0; e < D_; e += 4) {
    float4 a = *(const float4*)(qs + e);
    float4 b = *(const float4*)(wr + e);
    dot += a.x * b.x + a.y * b.y + a.z * b.z + a.w * b.w;
  }
  out[(size_t)q * V2_ + v] = 1.f / (1.f + expf(-dot));
}

extern "C" void kernel_launch(void* const* d_in, const int* in_sizes, int n_in,
                              void* d_out, int out_size, void* d_ws, size_t ws_size,
                              hipStream_t stream) {
  const int* qd = (const int*)d_in[0];
  const int* qp = (const int*)d_in[1];
  const int* qm = (const int*)d_in[2];
  const int* md = (const int*)d_in[3];
  const int* mp = (const int*)d_in[4];
  const int* mm = (const int*)d_in[5];
  const float* emb = (const float*)d_in[6];
  const float* Wih = (const float*)d_in[7];
  const float* Whh = (const float*)d_in[8];
  const float* bih = (const float*)d_in[9];
  const float* bhh = (const float*)d_in[10];
  const float* W2  = (const float*)d_in[11];
  const float* b2  = (const float*)d_in[12];
  const float* Wo  = (const float*)d_in[13];
  const float* bo  = (const float*)d_in[14];
  const int* kptr  = (const int*)d_in[15];
  float* out = (float*)d_out;
  (void)in_sizes; (void)n_in; (void)out_size; (void)ws_size;

  char* ws = (char*)d_ws;
  size_t off = 0;
  auto alloc = [&](size_t nfloats) {
    float* pp = (float*)(ws + off);
    off += ((nfloats * sizeof(float) + 255) & ~(size_t)255);
    return pp;
  };
  float* e_full  = alloc((size_t)NV * D_);
  float* e_nomed = alloc((size_t)NV * D_);
  float* gx      = alloc((size_t)NV * 768);
  float* hs_all  = alloc((size_t)NV * D_);
  float* tmp     = alloc((size_t)NV * D_);
  float* enc     = alloc((size_t)NROWS * D_);
  float* norms   = alloc(NROWS);
  float* sims    = alloc((size_t)NQ * NM);
  float* outq    = alloc((size_t)NQ * D_);
  float* WT4     = alloc((size_t)256 * 768);

  embed_kernel<<<NV, 256, 0, stream>>>(qd, qp, qm, md, mp, mm, emb, e_nomed, e_full);

  transpose_whh<<<192, 256, 0, stream>>>(Whh, WT4);

  {
    int nrt = (NV + BM - 1) / BM, nct = 768 / BN;
    gemm_nt_bias<<<nrt * nct, 256, 0, stream>>>(e_full, Wih, bih, gx, NV, 768, nct);
  }

  gru_all<<<NPAT / 3, 1024, 0, stream>>>(gx, WT4, bhh, hs_all);

  {
    int nrt = (NV + BM - 1) / BM, nct = 256 / BN;
    gemm_nt_bias<<<nrt * nct, 256, 0, stream>>>(hs_all, W2, b2, tmp, NV, 256, nct);
  }

  enc_kernel<<<NPAT, 256, 0, stream>>>(tmp, e_full, e_nomed, enc, norms);
  sims_kernel<<<dim3(NM / 256, NQ), 256, 0, stream>>>(enc, norms, sims);
  topk_gather<<<NQ, 256, 0, stream>>>(sims, enc, kptr, outq);
  out_kernel<<<dim3((V2_ + 255) / 256, NQ), 256, 0, stream>>>(outq, Wo, bo, out);
}

// Round 12
// 362.305 us; speedup vs baseline: 2.8249x; 1.0706x over previous
//
#include <hip/hip_runtime.h>
#include <math.h>

constexpr int V0_ = 2000, V1_ = 1500, V2_ = 500;
constexpr int D_ = 256, T_ = 16, P_ = 512;
constexpr int LD_ = 24, LP_ = 16, LM_ = 24;
constexpr int NPAT = P_ + 1;        // 513 (512 mem + 1 query)
constexpr int NV   = NPAT * T_;     // 8208 visits
constexpr int NM   = P_ * (T_ - 1); // 7680 memory rows
constexpr int NQ   = T_ - 1;        // 15 query rows
constexpr int NROWS = NPAT * NQ;    // 7695 encoder rows (M rows then Q rows)
constexpr float THRESH_ = 0.8f;
constexpr float EPS_ = 1e-6f;

__device__ __forceinline__ float sigmoidf_(float x) { return 1.0f / (1.0f + expf(-x)); }

// bf16-in-u32 unpack: low half = bits<<16, high half = bits&0xffff0000
#define BLO(u) __uint_as_float((u) << 16)
#define BHI(u) __uint_as_float((u) & 0xffff0000u)

// ---------------- K1: embedding gather-sums ----------------
__global__ void embed_kernel(const int* __restrict__ qd, const int* __restrict__ qp,
                             const int* __restrict__ qm, const int* __restrict__ md,
                             const int* __restrict__ mp, const int* __restrict__ mm,
                             const float* __restrict__ emb,
                             float* __restrict__ e_nomed, float* __restrict__ e_full) {
  int b = blockIdx.x;           // 0..NV-1
  int p = b / T_, t = b % T_;
  int tid = threadIdx.x;
  __shared__ int codes[64];
  if (tid < 64) {
    int c;
    if (tid < LD_) {
      c = (p < P_) ? md[(p * T_ + t) * LD_ + tid] : qd[t * LD_ + tid];
    } else if (tid < LD_ + LP_) {
      int i = tid - LD_;
      c = ((p < P_) ? mp[(p * T_ + t) * LP_ + i] : qp[t * LP_ + i]) + V0_;
    } else {
      int i = tid - LD_ - LP_;
      c = ((p < P_) ? mm[(p * T_ + t) * LM_ + i] : qm[t * LM_ + i]) + V0_ + V1_;
    }
    codes[tid] = c;
  }
  __syncthreads();
  float s0 = 0.f, s1 = 0.f;
  #pragma unroll 8
  for (int i = 0; i < LD_ + LP_; ++i) s0 += emb[codes[i] * D_ + tid];
  #pragma unroll 8
  for (int i = LD_ + LP_; i < 64; ++i) s1 += emb[codes[i] * D_ + tid];
  e_nomed[(size_t)b * D_ + tid] = s0;
  e_full[(size_t)b * D_ + tid]  = s0 + s1;
}

// ---------------- K2: C[M,N] = A[M,256] * B[N,256]^T + bias[N] ----------------
#define BM 128
#define BN 64
#define BK 32
__global__ void gemm_nt_bias(const float* __restrict__ A, const float* __restrict__ B,
                             const float* __restrict__ bias, float* __restrict__ C,
                             int M, int N, int nct) {
  const int K = 256;
  __shared__ float As[BK][BM + 5];
  __shared__ float Bs[BK][BN + 5];
  int nb = gridDim.x;
  int b = blockIdx.x;
  int q = nb >> 3, r = nb & 7;
  int xcd = b & 7, i0 = b >> 3;
  int nbb = (xcd < r) ? (xcd * (q + 1) + i0) : (r * (q + 1) + (xcd - r) * q + i0);
  int rt = nbb / nct, ct = nbb - rt * nct;
  int r0 = rt * BM;
  int c0 = ct * BN;
  int tid = threadIdx.x;
  int tx = tid & 15, ty = tid >> 4;
  float acc[8][4];
  #pragma unroll
  for (int i = 0; i < 8; ++i)
    #pragma unroll
    for (int j = 0; j < 4; ++j) acc[i][j] = 0.f;

  for (int k0 = 0; k0 < K; k0 += BK) {
    #pragma unroll
    for (int i = 0; i < 4; ++i) {           // A tile 128x32
      int flat = i * 256 + tid;             // one float4 each
      int rr = flat >> 3;
      int kq = flat & 7;
      float4 v = make_float4(0.f, 0.f, 0.f, 0.f);
      if (r0 + rr < M) v = *(const float4*)(A + (size_t)(r0 + rr) * K + k0 + kq * 4);
      As[kq * 4 + 0][rr] = v.x; As[kq * 4 + 1][rr] = v.y;
      As[kq * 4 + 2][rr] = v.z; As[kq * 4 + 3][rr] = v.w;
    }
    #pragma unroll
    for (int i = 0; i < 2; ++i) {           // B tile 64x32 (N%64==0, no guard)
      int flat = i * 256 + tid;
      int rr = flat >> 3;
      int kq = flat & 7;
      float4 v = *(const float4*)(B + (size_t)(c0 + rr) * K + k0 + kq * 4);
      Bs[kq * 4 + 0][rr] = v.x; Bs[kq * 4 + 1][rr] = v.y;
      Bs[kq * 4 + 2][rr] = v.z; Bs[kq * 4 + 3][rr] = v.w;
    }
    __syncthreads();
    #pragma unroll
    for (int kk = 0; kk < BK; ++kk) {
      float4 a0 = *(const float4*)&As[kk][ty * 8];
      float4 a1 = *(const float4*)&As[kk][ty * 8 + 4];
      float4 bv = *(const float4*)&Bs[kk][tx * 4];
      float av[8] = {a0.x, a0.y, a0.z, a0.w, a1.x, a1.y, a1.z, a1.w};
      float bw[4] = {bv.x, bv.y, bv.z, bv.w};
      #pragma unroll
      for (int i = 0; i < 8; ++i)
        #pragma unroll
        for (int j = 0; j < 4; ++j) acc[i][j] = fmaf(av[i], bw[j], acc[i][j]);
    }
    __syncthreads();
  }
  float bv0 = bias[c0 + tx * 4 + 0], bv1 = bias[c0 + tx * 4 + 1];
  float bv2 = bias[c0 + tx * 4 + 2], bv3 = bias[c0 + tx * 4 + 3];
  #pragma unroll
  for (int i = 0; i < 8; ++i) {
    int rr = r0 + ty * 8 + i;
    if (rr < M) {
      float4 o = make_float4(acc[i][0] + bv0, acc[i][1] + bv1,
                             acc[i][2] + bv2, acc[i][3] + bv3);
      *(float4*)(C + (size_t)rr * N + c0 + tx * 4) = o;
    }
  }
}

// ---------------- K2b: Whh [768][256] f32 -> packed bf16 ----------------
// Wp uint4-index = (e8*3 + g)*256 + d holds Whh[g*256+d][e8*8 .. e8*8+7]
// as 8 bf16 (RNE), pairs packed (even->lo, odd->hi).
__global__ void pack_whh(const float* __restrict__ Whh, uint4* __restrict__ Wp) {
  int b = blockIdx.x;            // 0..95 = e8*3 + g
  int e8 = b / 3, g = b - e8 * 3;
  int d = threadIdx.x;
  const float* src = Whh + (size_t)(g * 256 + d) * 256 + e8 * 8;
  unsigned rbits[8];
  #pragma unroll
  for (int j = 0; j < 8; ++j) {
    unsigned u = __float_as_uint(src[j]);
    rbits[j] = (u + 0x7fffu + ((u >> 16) & 1u)) >> 16;   // round-nearest-even
  }
  uint4 o;
  o.x = rbits[0] | (rbits[1] << 16);
  o.y = rbits[2] | (rbits[3] << 16);
  o.z = rbits[4] | (rbits[5] << 16);
  o.w = rbits[6] | (rbits[7] << 16);
  Wp[(size_t)b * 256 + d] = o;
}

// ---------------- K3: persistent GRU, bf16 weights, distributed epilogue ------
// 171 blocks x 1024 threads; block owns 3 patients. Dot phase: quarter qt
// handles e in [qt*64, qt*64+64) via 8 uint4 loads (8 bf16 each) per gate.
// ALL quarters dump partials to LDS; epilogue distributed over 768 threads
// (one per (patient, d)). Per-CU L2 weight stream halved vs f32.
__global__ __launch_bounds__(1024) void gru_all(const float* __restrict__ gx,
                                                const uint4* __restrict__ Wp,
                                                const float* __restrict__ bhh,
                                                float* __restrict__ hs_all) {
  int tid = threadIdx.x;
  int d = tid & 255;
  int qt = tid >> 8;          // 0..3
  int p0 = blockIdx.x * 3;
  __shared__ float hL[3][D_];
  __shared__ float part[4][3][3][D_];   // [quarter][patient][gate][d]
  if (qt == 0) { hL[0][d] = 0.f; hL[1][d] = 0.f; hL[2][d] = 0.f; }
  float brd = bhh[d], bzd = bhh[D_ + d], bnd = bhh[2 * D_ + d];
  __syncthreads();

  const uint4* wbase = Wp + d;
  for (int t = 0; t < T_; ++t) {
    float ar[3] = {0.f, 0.f, 0.f}, az[3] = {0.f, 0.f, 0.f}, an[3] = {0.f, 0.f, 0.f};
    int e80 = qt << 3;
    #pragma unroll 4
    for (int e8 = e80; e8 < e80 + 8; ++e8) {
      const uint4* wp = wbase + (size_t)(e8 * 3) * 256;
      uint4 w0 = wp[0];      // gate r, e = e8*8 .. e8*8+7
      uint4 w1 = wp[256];    // gate z
      uint4 w2 = wp[512];    // gate n
      #pragma unroll
      for (int i = 0; i < 3; ++i) {
        float4 ha = *(const float4*)&hL[i][e8 << 3];
        float4 hb = *(const float4*)&hL[i][(e8 << 3) + 4];
        ar[i] = fmaf(ha.x, BLO(w0.x), ar[i]); ar[i] = fmaf(ha.y, BHI(w0.x), ar[i]);
        ar[i] = fmaf(ha.z, BLO(w0.y), ar[i]); ar[i] = fmaf(ha.w, BHI(w0.y), ar[i]);
        ar[i] = fmaf(hb.x, BLO(w0.z), ar[i]); ar[i] = fmaf(hb.y, BHI(w0.z), ar[i]);
        ar[i] = fmaf(hb.z, BLO(w0.w), ar[i]); ar[i] = fmaf(hb.w, BHI(w0.w), ar[i]);
        az[i] = fmaf(ha.x, BLO(w1.x), az[i]); az[i] = fmaf(ha.y, BHI(w1.x), az[i]);
        az[i] = fmaf(ha.z, BLO(w1.y), az[i]); az[i] = fmaf(ha.w, BHI(w1.y), az[i]);
        az[i] = fmaf(hb.x, BLO(w1.z), az[i]); az[i] = fmaf(hb.y, BHI(w1.z), az[i]);
        az[i] = fmaf(hb.z, BLO(w1.w), az[i]); az[i] = fmaf(hb.w, BHI(w1.w), az[i]);
        an[i] = fmaf(ha.x, BLO(w2.x), an[i]); an[i] = fmaf(ha.y, BHI(w2.x), an[i]);
        an[i] = fmaf(ha.z, BLO(w2.y), an[i]); an[i] = fmaf(ha.w, BHI(w2.y), an[i]);
        an[i] = fmaf(hb.x, BLO(w2.z), an[i]); an[i] = fmaf(hb.y, BHI(w2.z), an[i]);
        an[i] = fmaf(hb.z, BLO(w2.w), an[i]); an[i] = fmaf(hb.w, BHI(w2.w), an[i]);
      }
    }
    #pragma unroll
    for (int i = 0; i < 3; ++i) {
      part[qt][i][0][d] = ar[i];
      part[qt][i][1][d] = az[i];
      part[qt][i][2][d] = an[i];
    }
    __syncthreads();
    if (tid < 768) {
      int i = tid >> 8;          // patient 0..2 (d == tid & 255)
      int p = p0 + i;
      const float* gxp = gx + (size_t)(p * T_ + t) * 768;
      float arf = part[0][i][0][d] + part[1][i][0][d] + part[2][i][0][d] + part[3][i][0][d];
      float azf = part[0][i][1][d] + part[1][i][1][d] + part[2][i][1][d] + part[3][i][1][d];
      float anf = part[0][i][2][d] + part[1][i][2][d] + part[2][i][2][d] + part[3][i][2][d];
      float r = sigmoidf_(gxp[d] + brd + arf);
      float z = sigmoidf_(gxp[D_ + d] + bzd + azf);
      // torch GRU: n = tanh(xn + r*(h@Whh_n.T + bhh_n)) -- bhh_n INSIDE r gate
      float n = tanhf(gxp[2 * D_ + d] + r * (anf + bnd));
      float hn = (1.f - z) * n + z * hL[i][d];
      hL[i][d] = hn;
      hs_all[(size_t)(p * T_ + t) * D_ + d] = hn;
    }
    __syncthreads();
  }
}

// ---------------- K4: tanh(tmp)*e_full cumsum -> encoders (+fused norms) ------
__global__ void enc_kernel(const float* __restrict__ tmp, const float* __restrict__ e_full,
                           const float* __restrict__ e_nomed, float* __restrict__ enc,
                           float* __restrict__ norms) {
  int p = blockIdx.x, d = threadIdx.x;
  __shared__ float red[4];
  float acc = 0.f;
  for (int t = 0; t < NQ; ++t) {   // t = 0..14
    size_t vi = (size_t)(p * T_ + t) * D_ + d;
    acc += tanhf(tmp[vi]) * e_full[vi];
    float ev = acc + e_nomed[(size_t)(p * T_ + t + 1) * D_ + d];
    int row = p * NQ + t;
    enc[(size_t)row * D_ + d] = ev;
    float s = ev * ev;
    #pragma unroll
    for (int off = 32; off > 0; off >>= 1) s += __shfl_down(s, off, 64);
    if ((d & 63) == 0) red[d >> 6] = s;
    __syncthreads();
    if (d == 0) norms[row] = fmaxf(sqrtf(red[0] + red[1] + red[2] + red[3]), EPS_);
    __syncthreads();
  }
}

// ---------------- K6: cosine sims [NQ, NM] ----------------
__global__ void sims_kernel(const float* __restrict__ enc, const float* __restrict__ norms,
                            float* __restrict__ sims) {
  int q = blockIdx.y;
  int m = blockIdx.x * 256 + threadIdx.x;
  __shared__ float qs[D_];
  qs[threadIdx.x] = enc[(size_t)(NM + q) * D_ + threadIdx.x];
  __syncthreads();
  const float* mrow = enc + (size_t)m * D_;
  float dot = 0.f;
  #pragma unroll 8
  for (int e = 0; e < D_; e += 4) {
    float4 a = *(const float4*)(qs + e);
    float4 b = *(const float4*)(mrow + e);
    dot += a.x * b.x + a.y * b.y + a.z * b.z + a.w * b.w;
  }
  sims[(size_t)q * NM + m] = dot / (norms[NM + q] * norms[m]);
}

// ---------------- K7: threshold-first top-k + weighted gather ----------------
#define CAP 4096
__global__ void topk_gather(const float* __restrict__ sims, const float* __restrict__ enc,
                            const int* __restrict__ kptr, float* __restrict__ outq) {
  int q = blockIdx.x, tid = threadIdx.x;
  __shared__ int cnt;
  __shared__ float cv[CAP];
  __shared__ int ci[CAP];
  __shared__ float selv[64];
  __shared__ int seli[64];
  __shared__ float rv[256];
  __shared__ int ri[256];
  if (tid == 0) cnt = 0;
  __syncthreads();
  const float* sq = sims + (size_t)q * NM;
  for (int j = tid; j < NM; j += 256) {
    float v = sq[j];
    if (v > THRESH_) {
      int slot = atomicAdd(&cnt, 1);
      if (slot < CAP) { cv[slot] = v; ci[slot] = j; }
    }
  }
  __syncthreads();
  int k = kptr[0];
  if (k > 64) k = 64;
  if (k < 0) k = 0;
  int n = cnt; if (n > CAP) n = CAP;
  int nsel;
  if (n <= k) {   // all candidates contribute (they're all > THRESH and within top-k)
    nsel = n;
    if (tid < n) { selv[tid] = cv[tid]; seli[tid] = ci[tid]; }
  } else {        // pick k largest among candidates (tie: lower index)
    nsel = k;
    for (int it = 0; it < k; ++it) {
      float best = -3e38f; int bslot = -1;
      for (int j = tid; j < n; j += 256) {
        float v = cv[j];
        if (v > best) { best = v; bslot = j; }
        else if (v == best && bslot >= 0 && ci[j] < ci[bslot]) { bslot = j; }
      }
      rv[tid] = best; ri[tid] = bslot;
      __syncthreads();
      for (int off = 128; off > 0; off >>= 1) {
        if (tid < off) {
          float v2 = rv[tid + off]; int s2 = ri[tid + off];
          if (s2 >= 0 && (ri[tid] < 0 || v2 > rv[tid] ||
                          (v2 == rv[tid] && ci[s2] < ci[ri[tid]]))) {
            rv[tid] = v2; ri[tid] = s2;
          }
        }
        __syncthreads();
      }
      if (tid == 0) {
        int s = ri[0];
        selv[it] = rv[0]; seli[it] = ci[s];
        cv[s] = -3e38f;   // remove
      }
      __syncthreads();
    }
  }
  __syncthreads();
  float o = enc[(size_t)(NM + q) * D_ + tid];   // Q[q][d]
  for (int j = 0; j < nsel; ++j)
    o += selv[j] * enc[(size_t)seli[j] * D_ + tid];
  outq[(size_t)q * D_ + tid] = o;
}

// ---------------- K8: output projection + sigmoid ----------------
__global__ void out_kernel(const float* __restrict__ outq, const float* __restrict__ Wo,
                           const float* __restrict__ bo, float* __restrict__ out) {
  int q = blockIdx.y;
  int v = blockIdx.x * 256 + threadIdx.x;
  __shared__ float qs[D_];
  qs[threadIdx.x] = outq[(size_t)q * D_ + threadIdx.x];
  __syncthreads();
  if (v >= V2_) return;
  const float* wr = Wo + (size_t)v * D_;
  float dot = bo[v];
  #pragma unroll 8
  for (int e = 0; e < D_; e += 4) {
    float4 a = *(const float4*)(qs + e);
    float4 b = *(const float4*)(wr + e);
    dot += a.x * b.x + a.y * b.y + a.z * b.z + a.w * b.w;
  }
  out[(size_t)q * V2_ + v] = 1.f / (1.f + expf(-dot));
}

extern "C" void kernel_launch(void* const* d_in, const int* in_sizes, int n_in,
                              void* d_out, int out_size, void* d_ws, size_t ws_size,
                              hipStream_t stream) {
  const int* qd = (const int*)d_in[0];
  const int* qp = (const int*)d_in[1];
  const int* qm = (const int*)d_in[2];
  const int* md = (const int*)d_in[3];
  const int* mp = (const int*)d_in[4];
  const int* mm = (const int*)d_in[5];
  const float* emb = (const float*)d_in[6];
  const float* Wih = (const float*)d_in[7];
  const float* Whh = (const float*)d_in[8];
  const float* bih = (const float*)d_in[9];
  const float* bhh = (const float*)d_in[10];
  const float* W2  = (const float*)d_in[11];
  const float* b2  = (const float*)d_in[12];
  const float* Wo  = (const float*)d_in[13];
  const float* bo  = (const float*)d_in[14];
  const int* kptr  = (const int*)d_in[15];
  float* out = (float*)d_out;
  (void)in_sizes; (void)n_in; (void)out_size; (void)ws_size;

  char* ws = (char*)d_ws;
  size_t off = 0;
  auto alloc = [&](size_t nfloats) {
    float* pp = (float*)(ws + off);
    off += ((nfloats * sizeof(float) + 255) & ~(size_t)255);
    return pp;
  };
  float* e_full  = alloc((size_t)NV * D_);
  float* e_nomed = alloc((size_t)NV * D_);
  float* gx      = alloc((size_t)NV * 768);
  float* hs_all  = alloc((size_t)NV * D_);
  float* tmp     = alloc((size_t)NV * D_);
  float* enc     = alloc((size_t)NROWS * D_);
  float* norms   = alloc(NROWS);
  float* sims    = alloc((size_t)NQ * NM);
  float* outq    = alloc((size_t)NQ * D_);
  uint4* Wp      = (uint4*)alloc((size_t)96 * 256 * 4);  // 96*256 uint4 (bf16 Whh)

  embed_kernel<<<NV, 256, 0, stream>>>(qd, qp, qm, md, mp, mm, emb, e_nomed, e_full);

  pack_whh<<<96, 256, 0, stream>>>(Whh, Wp);

  {
    int nrt = (NV + BM - 1) / BM, nct = 768 / BN;
    gemm_nt_bias<<<nrt * nct, 256, 0, stream>>>(e_full, Wih, bih, gx, NV, 768, nct);
  }

  gru_all<<<NPAT / 3, 1024, 0, stream>>>(gx, Wp, bhh, hs_all);

  {
    int nrt = (NV + BM - 1) / BM, nct = 256 / BN;
    gemm_nt_bias<<<nrt * nct, 256, 0, stream>>>(hs_all, W2, b2, tmp, NV, 256, nct);
  }

  enc_kernel<<<NPAT, 256, 0, stream>>>(tmp, e_full, e_nomed, enc, norms);
  sims_kernel<<<dim3(NM / 256, NQ), 256, 0, stream>>>(enc, norms, sims);
  topk_gather<<<NQ, 256, 0, stream>>>(sims, enc, kptr, outq);
  out_kernel<<<dim3((V2_ + 255) / 256, NQ), 256, 0, stream>>>(outq, Wo, bo, out);
}